// Round 1
// baseline (279.008 us; speedup 1.0000x reference)
//
#include <hip/hip_runtime.h>

#define NSMP 44100
#define NKNOT 100
#define NCC 6            // NC in reference
#define NAA 7            // NA in reference = number of taps
#define NTH 256
#define RING 1024
#define SEG ((NSMP + NTH - 1) / NTH)   // 173

__device__ __forceinline__ float sigm(float x) { return 1.0f / (1.0f + expf(-x)); }

// Evaluate NCOLS columns of the natural cubic spline at sample t.
template <int NCOLS>
__device__ __forceinline__ void eval_row(const float P[][NAA], const float M[][NAA],
                                         int t, float* res) {
    const float H = 1.0f / 99.0f;
    float tt = (float)t * (1.0f / (float)(NSMP - 1));
    int idx = (int)(tt * 99.0f);
    if (idx > NKNOT - 2) idx = NKNOT - 2;
    float f = tt - (float)idx * H;
#pragma unroll
    for (int c = 0; c < NCOLS; ++c) {
        float y0 = P[idx][c], y1 = P[idx + 1][c];
        float m0 = M[idx][c], m1 = M[idx + 1][c];
        float b  = (y1 - y0) * 99.0f - H * (2.0f * m0 + m1) * (1.0f / 6.0f);
        float cc = 0.5f * m0;
        float dd = (m1 - m0) * (99.0f / 6.0f);
        res[c] = y0 + f * (b + f * (cc + f * dd));
    }
}

__global__ __launch_bounds__(NTH, 1) void diffks_kernel(
    const float* __restrict__ dlf,   // delay_len_frames (100)
    const float* __restrict__ rg,    // raw_gain (1)
    const float* __restrict__ rcf,   // raw_coeff_frames (100*6)
    const float* __restrict__ exc,   // excitation (44100)
    const float* __restrict__ ecoef, // exc_coefficients (44100)
    float* __restrict__ out)         // y (44100)
{
    __shared__ float P[NKNOT][NAA];   // spline knot values (delay | b0..b5)
    __shared__ float M[NKNOT][NAA];   // spline second derivatives
    __shared__ float CP[NKNOT];       // Thomas c' coefficients (98 used)
    __shared__ float ring[RING];      // y history ring buffer
    __shared__ float scanP[NTH];
    __shared__ float scanQ[NTH];
    __shared__ int   s_minz;

    const int tid = threadIdx.x;
    const float H = 1.0f / 99.0f;

    if (tid == 0) s_minz = 0x7fffffff;
    for (int i = tid; i < RING; i += NTH) ring[i] = 0.0f;

    // ---------------- Phase A: knot params (sigmoid / normalize / gain) -----
    if (tid < NKNOT) {
        float g = sigm(rg[0]);
        float s[NCC];
        float sum = 0.0f;
#pragma unroll
        for (int j = 0; j < NCC; ++j) { s[j] = sigm(rcf[tid * NCC + j]); sum += s[j]; }
        P[tid][0] = dlf[tid];
#pragma unroll
        for (int j = 0; j < NCC; ++j) P[tid][j + 1] = s[j] / sum * g;
    }
    __syncthreads();

    // ---------------- Phase B: tridiagonal solve (Thomas), M = spline'' -----
    if (tid == 0) {
        float cp = 0.25f;          // h / (4h)
        CP[0] = cp;
        for (int i = 1; i < NKNOT - 2; ++i) {
            cp = H / (4.0f * H - H * CP[i - 1]);
            CP[i] = cp;
        }
    }
    __syncthreads();
    if (tid < NAA) {
        int c = tid;
        float rhs0  = 6.0f * (P[2][c] - 2.0f * P[1][c] + P[0][c]) / H;
        float dprev = rhs0 / (4.0f * H);
        M[1][c] = dprev;
        for (int i = 1; i < NKNOT - 2; ++i) {
            float rhs = 6.0f * (P[i + 2][c] - 2.0f * P[i + 1][c] + P[i][c]) / H;
            float m   = 4.0f * H - H * CP[i - 1];
            float d   = (rhs - H * dprev) / m;
            M[i + 1][c] = d;
            dprev = d;
        }
        float nxt = M[NKNOT - 2][c];           // Min[97]
        for (int i = NKNOT - 4; i >= 0; --i) { // i = 96..0 -> rows i+1
            float v = M[i + 1][c] - CP[i] * nxt;
            M[i + 1][c] = v;
            nxt = v;
        }
        M[0][c] = 0.0f;
        M[NKNOT - 1][c] = 0.0f;
    }
    __syncthreads();

    // ---------------- Phase C: min integer delay (for safe window size) -----
    {
        int zl = 0x7fffffff;
        for (int t = tid; t < NSMP; t += NTH) {
            float d0;
            eval_row<1>(P, M, t, &d0);
            int z = (int)floorf(d0);
            zl = min(zl, z);
        }
        atomicMin(&s_minz, zl);
    }

    // ---------------- Phase D: order-1 LPC via segmented parallel scan ------
    {
        int start = tid * SEG;
        int end   = min(start + SEG, NSMP);
        float p = 1.0f, q = 0.0f;
        for (int t = start; t < end; ++t) {
            float a = ecoef[t];
            q = fmaf(-a, q, exc[t]);   // q = x[t] - a[t]*q
            p *= -a;
        }
        scanP[tid] = p;
        scanQ[tid] = q;
        __syncthreads();
        if (tid == 0) {
            float Y = 0.0f;
            for (int k = 0; k < NTH; ++k) {
                float Pk = scanP[k], Qk = scanQ[k];
                scanQ[k] = Y;                 // exclusive: initial y for segment k
                Y = fmaf(Pk, Y, Qk);
            }
        }
        __syncthreads();
        float y = scanQ[tid];
        for (int t = start; t < end; ++t) {
            y = fmaf(-ecoef[t], y, exc[t]);
            out[t] = y;                       // stage x2 in d_out
        }
    }
    __syncthreads();

    // ---------------- Phase E: sparse high-order LPC, windowed --------------
    int minz = s_minz;
    int C = min(NTH, minz + 1);
    if (C < 1) C = 1;

    for (int W = 0; W < NSMP; W += C) {
        int t = W + tid;
        bool act = (tid < C) && (t < NSMP);
        float val[NAA];
        int z = 0;
        float xv = 0.0f;
        if (act) {
            float r[NAA];
            eval_row<NAA>(P, M, t, r);        // r[0]=delay, r[1..6]=b0..b5
            float delay = r[0];
            float fl = floorf(delay);
            z = (int)fl;
            float alfa = delay - fl;
            float om = 1.0f - alfa;
            val[0] = -om * r[1];
#pragma unroll
            for (int j = 1; j < NAA - 1; ++j) val[j] = -(alfa * r[j] + om * r[j + 1]);
            val[NAA - 1] = -alfa * r[NCC];
            xv = out[t];                       // x2[t], written in phase D
        }
        __syncthreads();   // previous window's ring writes -> visible
        if (act) {
            float acc = xv;
            int base = t - 1 - z;
#pragma unroll
            for (int j = 0; j < NAA; ++j) {
                int src = base - j;
                float yv = (src >= 0) ? ring[src & (RING - 1)] : 0.0f;
                acc = fmaf(-val[j], yv, acc);
            }
            ring[t & (RING - 1)] = acc;
            out[t] = acc;
        }
    }
}

extern "C" void kernel_launch(void* const* d_in, const int* in_sizes, int n_in,
                              void* d_out, int out_size, void* d_ws, size_t ws_size,
                              hipStream_t stream) {
    const float* dlf   = (const float*)d_in[0];
    const float* rg    = (const float*)d_in[1];
    const float* rcf   = (const float*)d_in[2];
    const float* exc   = (const float*)d_in[3];
    const float* ecoef = (const float*)d_in[4];
    float* out = (float*)d_out;
    hipLaunchKernelGGL(diffks_kernel, dim3(1), dim3(NTH), 0, stream,
                       dlf, rg, rcf, exc, ecoef, out);
}

// Round 2
// 149.364 us; speedup vs baseline: 1.8680x; 1.8680x over previous
//
#include <hip/hip_runtime.h>

#define NSMP 44100
#define NKNOT 100
#define NIV  (NKNOT - 1)      // 99 spline intervals
#define NCC 6                 // NC in reference
#define NAA 7                 // NA in reference = number of taps
#define NTH 256
#define RING 1024
#define SEG ((NSMP + NTH - 1) / NTH)   // 173
#define GW 8                  // windows precomputed per chunk

__device__ __forceinline__ float sigm(float x) { return 1.0f / (1.0f + expf(-x)); }

__device__ __forceinline__ void lean_barrier() {
    // lgkm drain only (ring LDS write visibility); skip vmcnt drain.
    asm volatile("s_waitcnt lgkmcnt(0)" ::: "memory");
    __builtin_amdgcn_s_barrier();
}

__global__ __launch_bounds__(NTH, 1) void diffks_kernel(
    const float* __restrict__ dlf,   // delay_len_frames (100)
    const float* __restrict__ rg,    // raw_gain (1)
    const float* __restrict__ rcf,   // raw_coeff_frames (100*6)
    const float* __restrict__ exc,   // excitation (44100)
    const float* __restrict__ ecoef, // exc_coefficients (44100)
    float* __restrict__ out)         // y (44100)
{
    __shared__ float P[NKNOT][NAA];   // knot values (delay | b0..b5)
    __shared__ float M[NKNOT][NAA];   // spline second derivatives
    __shared__ float CP[NKNOT];       // Thomas c' coefficients
    __shared__ float4 CO[NIV][8];     // per-interval poly coefs {a,b,c,d} per col
    __shared__ float ring[RING];      // y history ring
    __shared__ float wp[4], wq[4];    // wave scan totals
    __shared__ int   s_minz;

    const int tid = threadIdx.x;
    const int lane = tid & 63;
    const int wav  = tid >> 6;
    const float H = 1.0f / 99.0f;
    const float INV = 1.0f / (float)(NSMP - 1);

    if (tid == 0) s_minz = 0x7fffffff;
    for (int i = tid; i < RING; i += NTH) ring[i] = 0.0f;

    // ---------------- Phase A: knot params -------------------------------
    if (tid < NKNOT) {
        float g = sigm(rg[0]);
        float s[NCC];
        float sum = 0.0f;
#pragma unroll
        for (int j = 0; j < NCC; ++j) { s[j] = sigm(rcf[tid * NCC + j]); sum += s[j]; }
        P[tid][0] = dlf[tid];
#pragma unroll
        for (int j = 0; j < NCC; ++j) P[tid][j + 1] = s[j] / sum * g;
    }
    __syncthreads();

    // ---------------- Phase B: tridiagonal (Thomas) -----------------------
    if (tid == 0) {
        float cp = 0.25f;
        CP[0] = cp;
        for (int i = 1; i < NKNOT - 2; ++i) {
            cp = H / (4.0f * H - H * CP[i - 1]);
            CP[i] = cp;
        }
    }
    __syncthreads();
    if (tid < NAA) {
        int c = tid;
        float rhs0  = 6.0f * (P[2][c] - 2.0f * P[1][c] + P[0][c]) / H;
        float dprev = rhs0 / (4.0f * H);
        M[1][c] = dprev;
        for (int i = 1; i < NKNOT - 2; ++i) {
            float rhs = 6.0f * (P[i + 2][c] - 2.0f * P[i + 1][c] + P[i][c]) / H;
            float m   = 4.0f * H - H * CP[i - 1];
            float d   = (rhs - H * dprev) / m;
            M[i + 1][c] = d;
            dprev = d;
        }
        float nxt = M[NKNOT - 2][c];
        for (int i = NKNOT - 4; i >= 0; --i) {
            float v = M[i + 1][c] - CP[i] * nxt;
            M[i + 1][c] = v;
            nxt = v;
        }
        M[0][c] = 0.0f;
        M[NKNOT - 1][c] = 0.0f;
    }
    __syncthreads();

    // ---------------- Phase B': per-interval poly coefficients ------------
    for (int iv = tid; iv < NIV; iv += NTH) {
#pragma unroll
        for (int c = 0; c < NAA; ++c) {
            float y0 = P[iv][c], y1 = P[iv + 1][c];
            float m0 = M[iv][c], m1 = M[iv + 1][c];
            float b  = (y1 - y0) * 99.0f - H * (2.0f * m0 + m1) * (1.0f / 6.0f);
            CO[iv][c] = make_float4(y0, b, 0.5f * m0, (m1 - m0) * (99.0f / 6.0f));
        }
    }
    __syncthreads();

    // ---------------- Phase C: min integer delay --------------------------
    {
        int zl = 0x7fffffff;
        for (int t = tid; t < NSMP; t += NTH) {
            float tt = (float)t * INV;
            int idx = (int)(tt * 99.0f); if (idx > NIV - 1) idx = NIV - 1;
            float f = tt - (float)idx * H;
            float4 k = CO[idx][0];
            float d0 = k.x + f * (k.y + f * (k.z + f * k.w));
            zl = min(zl, (int)floorf(d0));
        }
        atomicMin(&s_minz, zl);
    }

    // ---------------- Phase D: order-1 LPC (segmented affine scan) --------
    {
        int start = tid * SEG;
        int end   = min(start + SEG, NSMP);
        float p = 1.0f, q = 0.0f;
#pragma unroll 4
        for (int t = start; t < end; ++t) {
            float a = ecoef[t];
            q = fmaf(-a, q, exc[t]);
            p *= -a;
        }
        // intra-wave inclusive affine scan (compose earlier-then-own)
#pragma unroll
        for (int d = 1; d < 64; d <<= 1) {
            float pp = __shfl_up(p, d);
            float qq = __shfl_up(q, d);
            if (lane >= d) { q = fmaf(p, qq, q); p *= pp; }
        }
        if (lane == 63) { wp[wav] = p; wq[wav] = q; }
        // intra-wave exclusive
        float pe = __shfl_up(p, 1);
        float qe = __shfl_up(q, 1);
        if (lane == 0) { pe = 1.0f; qe = 0.0f; }
        __syncthreads();
        float v = 0.0f;
        for (int w = 0; w < wav; ++w) v = fmaf(wp[w], v, wq[w]);
        float y = fmaf(pe, v, qe);
#pragma unroll 4
        for (int t = start; t < end; ++t) {
            y = fmaf(-ecoef[t], y, exc[t]);
            out[t] = y;                      // stage x2 in d_out
        }
    }
    __syncthreads();   // x2 visible to all threads; s_minz final

    // ---------------- Phase E: sparse high-order LPC -----------------------
    int C = min(NTH, s_minz + 1);
    if (C < 1) C = 1;

    for (int W0 = 0; W0 < NSMP; W0 += GW * C) {
        float vals[GW][NAA];
        float xs[GW], accs[GW];
        int bases[GW];

        // --- parallel precompute: taps, base index, x2 (off the serial chain)
#pragma unroll
        for (int g = 0; g < GW; ++g) {
            int t = W0 + g * C + tid;
            bool act = (tid < C) && (t < NSMP);
            if (act) {
                float tt = (float)t * INV;
                int idx = (int)(tt * 99.0f); if (idx > NIV - 1) idx = NIV - 1;
                float f = tt - (float)idx * H;
                float r[NAA];
#pragma unroll
                for (int c = 0; c < NAA; ++c) {
                    float4 k = CO[idx][c];
                    r[c] = k.x + f * (k.y + f * (k.z + f * k.w));
                }
                float fl = floorf(r[0]);
                float alfa = r[0] - fl;
                float om = 1.0f - alfa;
                vals[g][0] = -om * r[1];
#pragma unroll
                for (int j = 1; j < NAA - 1; ++j) vals[g][j] = -(alfa * r[j] + om * r[j + 1]);
                vals[g][NAA - 1] = -alfa * r[NCC];
                bases[g] = t - 1 - (int)fl;
                xs[g] = out[t];              // x2[t]
            }
        }

        // --- serial windows: only ring ops on the barrier chain
#pragma unroll
        for (int g = 0; g < GW; ++g) {
            int t = W0 + g * C + tid;
            bool act = (tid < C) && (t < NSMP);
            if (act) {
                int base = bases[g];
                float yv[NAA];
#pragma unroll
                for (int j = 0; j < NAA; ++j) {
                    int src = base - j;
                    yv[j] = (src >= 0) ? ring[src & (RING - 1)] : 0.0f;
                }
                // tree dot product
                float p0 = vals[g][0] * yv[0];
                float p1 = vals[g][1] * yv[1];
                float p2 = vals[g][2] * yv[2];
                float p3 = vals[g][3] * yv[3];
                float p4 = vals[g][4] * yv[4];
                float p5 = vals[g][5] * yv[5];
                float p6 = vals[g][6] * yv[6];
                float s = ((p0 + p1) + (p2 + p3)) + ((p4 + p5) + p6);
                float acc = xs[g] - s;
                ring[t & (RING - 1)] = acc;
                accs[g] = acc;
            }
            lean_barrier();
        }

        // --- flush outputs (off the chain; vmcnt never drained per window)
#pragma unroll
        for (int g = 0; g < GW; ++g) {
            int t = W0 + g * C + tid;
            if ((tid < C) && (t < NSMP)) out[t] = accs[g];
        }
    }
}

extern "C" void kernel_launch(void* const* d_in, const int* in_sizes, int n_in,
                              void* d_out, int out_size, void* d_ws, size_t ws_size,
                              hipStream_t stream) {
    const float* dlf   = (const float*)d_in[0];
    const float* rg    = (const float*)d_in[1];
    const float* rcf   = (const float*)d_in[2];
    const float* exc   = (const float*)d_in[3];
    const float* ecoef = (const float*)d_in[4];
    float* out = (float*)d_out;
    hipLaunchKernelGGL(diffks_kernel, dim3(1), dim3(NTH), 0, stream,
                       dlf, rg, rcf, exc, ecoef, out);
}